// Round 3
// baseline (2845.049 us; speedup 1.0000x reference)
//
#include <hip/hip_runtime.h>
#include <hip/hip_bf16.h>

// Problem dims
#define B_SZ   32
#define L_SZ   100
#define D_SZ   30000
#define CO_SZ  1000
#define NP_SZ  10
#define CLS_SZ 104
#define M_SZ   3200            // B*L
#define NSTEPS 938             // ceil(30000/32): last step has 16 valid k, 16 zero-padded
#define SPLITK 4

typedef __attribute__((ext_vector_type(4))) float        f32x4;
typedef __attribute__((ext_vector_type(8))) short        s16x8;
typedef __attribute__((ext_vector_type(4))) unsigned int u32x4;

__device__ __forceinline__ unsigned cvt_pk_bf16(float a, float b) {
  unsigned r;
  asm("v_cvt_pk_bf16_f32 %0, %1, %2" : "=v"(r) : "v"(a), "v"(b));
  return r;
}

// 16 fp32 (4x f32x4) -> 16 bf16 -> two 16B LDS stores.
// NOTE: if cvt_pk packs (hi,lo) swapped, the same k-permutation hits both A and B
// fragments, so the MFMA dot-product is unchanged — safe either way.
__device__ __forceinline__ void stage_write(short* dst, const f32x4* v) {
  u32x4 w0, w1;
  w0[0] = cvt_pk_bf16(v[0][0], v[0][1]);
  w0[1] = cvt_pk_bf16(v[0][2], v[0][3]);
  w0[2] = cvt_pk_bf16(v[1][0], v[1][1]);
  w0[3] = cvt_pk_bf16(v[1][2], v[1][3]);
  w1[0] = cvt_pk_bf16(v[2][0], v[2][1]);
  w1[1] = cvt_pk_bf16(v[2][2], v[2][3]);
  w1[2] = cvt_pk_bf16(v[3][0], v[3][1]);
  w1[3] = cvt_pk_bf16(v[3][2], v[3][3]);
  *(u32x4*)dst         = w0;
  *(((u32x4*)dst) + 1) = w1;
}

__device__ __forceinline__ void load16(f32x4* v, const float* src, bool ok) {
  if (ok) {
#pragma unroll
    for (int q = 0; q < 4; ++q) v[q] = *(const f32x4*)(src + q * 4);
  } else {
#pragma unroll
    for (int q = 0; q < 4; ++q) v[q] = (f32x4)(0.0f);
  }
}

// ---------------------------------------------------------------------------
// Kernel 1: C[m,n] += x[m, krange] . w[n, krange]   (bf16 MFMA, split-K atomics)
// 128x128 tile, BK=32, 4 waves (2x2 of 64x64), LDS rows padded to 40 shorts.
// ---------------------------------------------------------------------------
__global__ __launch_bounds__(256, 3) void gemm_k(const float* __restrict__ x,
                                                 const float* __restrict__ w,
                                                 float* __restrict__ C) {
  const int mBase = blockIdx.x * 128;
  const int nBase = blockIdx.y * 128;
  const int split = blockIdx.z;
  const int sBeg = (NSTEPS * split) / SPLITK;
  const int sEnd = (NSTEPS * (split + 1)) / SPLITK;

  const int tid = threadIdx.x;
  const int r   = tid >> 1;          // LDS row this thread stages (0..127)
  const int c0  = (tid & 1) * 16;    // k-offset within the 32-wide tile

  const float* aSrc = x + (size_t)(mBase + r) * D_SZ + c0;
  const float* bSrc = w + (size_t)(nBase + r) * D_SZ + c0;
  const bool   bOk  = (nBase + r) < CO_SZ;

  __shared__ short As[2][128 * 40];
  __shared__ short Bs[2][128 * 40];

  f32x4 acc[4][4];
#pragma unroll
  for (int i = 0; i < 4; ++i)
#pragma unroll
    for (int j = 0; j < 4; ++j) acc[i][j] = (f32x4)(0.0f);

  f32x4 ar[4], br[4];

  // Prologue: stage step sBeg into buf0, issue loads for sBeg+1
  {
    const int k0 = sBeg * 32;
    const bool ok = (k0 + c0) < D_SZ;
    load16(ar, aSrc + k0, ok);
    load16(br, bSrc + k0, ok && bOk);
    stage_write(&As[0][r * 40 + c0], ar);
    stage_write(&Bs[0][r * 40 + c0], br);
  }
  if (sBeg + 1 < sEnd) {
    const int k0 = (sBeg + 1) * 32;
    const bool ok = (k0 + c0) < D_SZ;
    load16(ar, aSrc + k0, ok);
    load16(br, bSrc + k0, ok && bOk);
  }
  __syncthreads();

  const int lane = tid & 63;
  const int wave = tid >> 6;
  const int wr = wave >> 1, wc = wave & 1;
  const int fr = lane & 15, kg = lane >> 4;
  const int aOff = (wr * 64 + fr) * 40 + kg * 8;   // shorts
  const int bOff = (wc * 64 + fr) * 40 + kg * 8;

  const int nsteps = sEnd - sBeg;
  int cur = 0;
  for (int i = 0; i < nsteps; ++i) {
    const int nxt = cur ^ 1;
    if (i + 1 < nsteps) {
      // write tile i+1 (regs were loaded last iter; vmcnt wait auto-inserted)
      stage_write(&As[nxt][r * 40 + c0], ar);
      stage_write(&Bs[nxt][r * 40 + c0], br);
      if (i + 2 < nsteps) {
        const int k0 = (sBeg + i + 2) * 32;
        const bool ok = (k0 + c0) < D_SZ;
        load16(ar, aSrc + k0, ok);
        load16(br, bSrc + k0, ok && bOk);
      }
    }
    s16x8 aF[4], bF[4];
#pragma unroll
    for (int q = 0; q < 4; ++q) aF[q] = *(const s16x8*)&As[cur][aOff + q * 640];
#pragma unroll
    for (int q = 0; q < 4; ++q) bF[q] = *(const s16x8*)&Bs[cur][bOff + q * 640];
#pragma unroll
    for (int a_ = 0; a_ < 4; ++a_)
#pragma unroll
      for (int b_ = 0; b_ < 4; ++b_)
        acc[a_][b_] = __builtin_amdgcn_mfma_f32_16x16x32_bf16(aF[a_], bF[b_], acc[a_][b_], 0, 0, 0);
    __syncthreads();
    cur = nxt;
  }

  // Epilogue: split-K accumulate into C (fp32). C/D layout: col=lane&15, row=(lane>>4)*4+e
#pragma unroll
  for (int a_ = 0; a_ < 4; ++a_) {
#pragma unroll
    for (int b_ = 0; b_ < 4; ++b_) {
      const int col = nBase + wc * 64 + b_ * 16 + fr;
      if (col < CO_SZ) {
        const int row0 = mBase + wr * 64 + a_ * 16 + kg * 4;
#pragma unroll
        for (int e = 0; e < 4; ++e)
          atomicAdd(&C[(size_t)(row0 + e) * CO_SZ + col], acc[a_][b_][e]);
      }
    }
  }
}

// ---------------------------------------------------------------------------
// Kernel 2: bias + relu + avg-pool(10)  ->  h[b][o*10+p]  (reference layout)
// ---------------------------------------------------------------------------
__global__ __launch_bounds__(256) void pool_k(const float* __restrict__ C,
                                              const float* __restrict__ conv_b,
                                              float* __restrict__ h) {
  const int t = blockIdx.x * 256 + threadIdx.x;   // 320000 total, exact
  const int o = t % CO_SZ;
  const int p = (t / CO_SZ) % NP_SZ;
  const int b = t / (CO_SZ * NP_SZ);
  const float bias = conv_b[o];
  const int rowBase = b * L_SZ + p * NP_SZ;
  float s = 0.0f;
#pragma unroll
  for (int l = 0; l < 10; ++l) {
    const float v = C[(size_t)(rowBase + l) * CO_SZ + o] + bias;
    s += fmaxf(v, 0.0f);
  }
  h[b * (CO_SZ * NP_SZ) + o * NP_SZ + p] = s * 0.1f;
}

// ---------------------------------------------------------------------------
// Kernel 3: per-batch L2-ish normalize + fc.  One block per batch row.
// ---------------------------------------------------------------------------
__global__ __launch_bounds__(256) void fc_k(const float* __restrict__ h,
                                            const float* __restrict__ fc_w,
                                            const float* __restrict__ fc_b,
                                            float* __restrict__ out) {
  __shared__ float hrow[CO_SZ * NP_SZ];  // 40 KB
  __shared__ float ssw[4];
  const int b = blockIdx.x;
  const int tid = threadIdx.x;
  const int lane = tid & 63;
  const int wave = tid >> 6;

  float ss = 0.0f;
  for (int j = tid; j < CO_SZ * NP_SZ; j += 256) {
    const float v = h[b * (CO_SZ * NP_SZ) + j];
    hrow[j] = v;
    ss += v * v;
  }
#pragma unroll
  for (int o = 32; o; o >>= 1) ss += __shfl_xor(ss, o);
  if (lane == 0) ssw[wave] = ss;
  __syncthreads();
  const float tot = ssw[0] + ssw[1] + ssw[2] + ssw[3];
  const float inv = 1.0f / sqrtf(1.0f + tot);

  for (int c = wave; c < CLS_SZ; c += 4) {
    float dot = 0.0f;
    const float* wrow = fc_w + (size_t)c * (CO_SZ * NP_SZ);
    for (int j = lane; j < CO_SZ * NP_SZ; j += 64) dot += hrow[j] * wrow[j];
#pragma unroll
    for (int o = 32; o; o >>= 1) dot += __shfl_xor(dot, o);
    if (lane == 0) out[b * CLS_SZ + c] = dot * inv + fc_b[c];
  }
}

extern "C" void kernel_launch(void* const* d_in, const int* in_sizes, int n_in,
                              void* d_out, int out_size, void* d_ws, size_t ws_size,
                              hipStream_t stream) {
  const float* x      = (const float*)d_in[0];
  const float* conv_w = (const float*)d_in[1];
  const float* conv_b = (const float*)d_in[2];
  const float* fc_w   = (const float*)d_in[3];
  const float* fc_b   = (const float*)d_in[4];
  float* out = (float*)d_out;

  float* C = (float*)d_ws;               // 3200*1000 fp32 = 12.8 MB
  float* h = C + (size_t)M_SZ * CO_SZ;   // 32*10000 fp32  = 1.28 MB

  // split-K atomics need zeroed C (ws is poisoned 0xAA before every launch)
  hipMemsetAsync(C, 0, (size_t)M_SZ * CO_SZ * sizeof(float), stream);

  dim3 grid(M_SZ / 128, (CO_SZ + 127) / 128, SPLITK);
  gemm_k<<<grid, 256, 0, stream>>>(x, conv_w, C);

  pool_k<<<(B_SZ * CO_SZ * NP_SZ) / 256, 256, 0, stream>>>(C, conv_b, h);

  fc_k<<<B_SZ, 256, 0, stream>>>(h, fc_w, fc_b, out);
}